// Round 1
// baseline (116.070 us; speedup 1.0000x reference)
//
#include <hip/hip_runtime.h>

#define NROWS 16384
#define DIM   1024          // floats per row
#define MARGIN_F 1.0f
#define EPS_F 1e-6f

// One WAVE (64 lanes) per row; 4 rows per 256-thread block.
// SINGLE streaming pass: accumulate the Gram terms (norms, dots, sums) so no
// data register survives past its consumption -> VGPR <= 64 -> 8 waves/SIMD
// (__launch_bounds__(256,8) pins it). Loss per row from:
//   sum_p = si^2*ni - 2*si*sp*dot_ip + sp^2*np + 2*eps*(si*Sa - sp*Sb) + D*eps^2
// which is the exact algebraic expansion of sum((a*si - b*sp + eps)^2).
__global__ __launch_bounds__(256, 8) void row_loss_kernel(
    const float* __restrict__ emb,
    const int*   __restrict__ pos_idx,
    const int*   __restrict__ neg_idx,
    float*       __restrict__ block_part)
{
    const int tid  = threadIdx.x;
    const int lane = tid & 63;
    const int wid  = tid >> 6;
    const int row  = blockIdx.x * 4 + wid;

    const int p = pos_idx[row];   // wave-uniform -> scalar loads
    const int n = neg_idx[row];

    const float4* xi = (const float4*)(emb + (size_t)row * DIM) + lane;
    const float4* xp = (const float4*)(emb + (size_t)p   * DIM) + lane;
    const float4* xn = (const float4*)(emb + (size_t)n   * DIM) + lane;

    float ni = 0.f, np_ = 0.f, nn = 0.f;     // squared norms
    float dip = 0.f, din = 0.f;              // dot(a,b), dot(a,c)
    float sa = 0.f, sb = 0.f, sc = 0.f;      // element sums (eps cross-terms)

    // Hand-pipelined: keep ~2 float4-groups per stream in flight; accumulators
    // consume each group as the next one loads. launch_bounds caps regalloc.
    float4 a0 = xi[0],   b0 = xp[0],   c0 = xn[0];
    float4 a1 = xi[64],  b1 = xp[64],  c1 = xn[64];

    #define ACC(A,B,C)                                                                                     \
        ni  = fmaf(A.x,A.x,ni);  ni  = fmaf(A.y,A.y,ni);  ni  = fmaf(A.z,A.z,ni);  ni  = fmaf(A.w,A.w,ni); \
        np_ = fmaf(B.x,B.x,np_); np_ = fmaf(B.y,B.y,np_); np_ = fmaf(B.z,B.z,np_); np_ = fmaf(B.w,B.w,np_);\
        nn  = fmaf(C.x,C.x,nn);  nn  = fmaf(C.y,C.y,nn);  nn  = fmaf(C.z,C.z,nn);  nn  = fmaf(C.w,C.w,nn); \
        dip = fmaf(A.x,B.x,dip); dip = fmaf(A.y,B.y,dip); dip = fmaf(A.z,B.z,dip); dip = fmaf(A.w,B.w,dip);\
        din = fmaf(A.x,C.x,din); din = fmaf(A.y,C.y,din); din = fmaf(A.z,C.z,din); din = fmaf(A.w,C.w,din);\
        sa += (A.x + A.y) + (A.z + A.w);                                                                   \
        sb += (B.x + B.y) + (B.z + B.w);                                                                   \
        sc += (C.x + C.y) + (C.z + C.w);

    float4 a2 = xi[128], b2 = xp[128], c2 = xn[128];
    ACC(a0, b0, c0)
    float4 a3 = xi[192], b3 = xp[192], c3 = xn[192];
    ACC(a1, b1, c1)
    ACC(a2, b2, c2)
    ACC(a3, b3, c3)
    #undef ACC

    // butterfly: every lane ends with full sums
    #pragma unroll
    for (int m = 1; m < 64; m <<= 1) {
        ni  += __shfl_xor(ni,  m, 64);
        np_ += __shfl_xor(np_, m, 64);
        nn  += __shfl_xor(nn,  m, 64);
        dip += __shfl_xor(dip, m, 64);
        din += __shfl_xor(din, m, 64);
        sa  += __shfl_xor(sa,  m, 64);
        sb  += __shfl_xor(sb,  m, 64);
        sc  += __shfl_xor(sc,  m, 64);
    }

    __shared__ float sm[4];
    if (lane == 0) {
        const float si = 1.0f / fmaxf(sqrtf(ni),  EPS_F);
        const float sp = 1.0f / fmaxf(sqrtf(np_), EPS_F);
        const float sn = 1.0f / fmaxf(sqrtf(nn),  EPS_F);
        const float de2 = (float)DIM * EPS_F * EPS_F;

        float sum_p = fmaf(si * si, ni, fmaf(sp * sp, np_, -2.f * si * sp * dip))
                    + 2.f * EPS_F * (si * sa - sp * sb) + de2;
        float sum_n = fmaf(si * si, ni, fmaf(sn * sn, nn, -2.f * si * sn * din))
                    + 2.f * EPS_F * (si * sa - sn * sc) + de2;

        float d_pos = sqrtf(fmaxf(sum_p, 0.f)) + EPS_F;
        float d_neg = sqrtf(fmaxf(sum_n, 0.f)) + EPS_F;
        float mq    = fmaxf(MARGIN_F - d_neg, EPS_F);
        sm[wid] = fmaf(d_pos, d_pos, mq * mq);
    }
    __syncthreads();
    if (tid == 0)
        block_part[blockIdx.x] = (sm[0] + sm[1]) + (sm[2] + sm[3]);
}

// 4096 block partials -> scalar. One block, 256 threads, 16 KiB read.
__global__ __launch_bounds__(256) void final_reduce_kernel(
    const float* __restrict__ part,
    float*       __restrict__ out)
{
    const int tid = threadIdx.x;
    const float4* p4 = (const float4*)part;   // 1024 float4
    float s = 0.f;
    #pragma unroll
    for (int j = 0; j < 4; ++j) {
        float4 v = p4[tid + 256 * j];
        s += (v.x + v.y) + (v.z + v.w);
    }
    #pragma unroll
    for (int m = 1; m < 64; m <<= 1) s += __shfl_xor(s, m, 64);

    __shared__ float sm[4];
    if ((tid & 63) == 0) sm[tid >> 6] = s;
    __syncthreads();
    if (tid == 0)
        out[0] = ((sm[0] + sm[1]) + (sm[2] + sm[3])) * (1.0f / (2.0f * (float)NROWS));
}

extern "C" void kernel_launch(void* const* d_in, const int* in_sizes, int n_in,
                              void* d_out, int out_size, void* d_ws, size_t ws_size,
                              hipStream_t stream) {
    const float* emb = (const float*)d_in[0];
    // d_in[1] = labels (unused by the loss itself)
    const int* pos = (const int*)d_in[2];
    const int* neg = (const int*)d_in[3];

    float* parts = (float*)d_ws;           // 4096 floats of scratch
    float* out   = (float*)d_out;

    row_loss_kernel<<<NROWS / 4, 256, 0, stream>>>(emb, pos, neg, parts);
    final_reduce_kernel<<<1, 256, 0, stream>>>(parts, out);
}

// Round 2
// 115.840 us; speedup vs baseline: 1.0020x; 1.0020x over previous
//
#include <hip/hip_runtime.h>

#define NROWS 16384
#define DIM   1024          // floats per row
#define F4_PER_ROW 256      // DIM/4
#define MARGIN_F 1.0f
#define EPS_F 1e-6f

#define ROWS_PER_WAVE   4
#define WAVES_PER_BLOCK 4
#define NBLOCKS (NROWS / (ROWS_PER_WAVE * WAVES_PER_BLOCK))   // 1024

// One WAVE (64 lanes) per 4 consecutive rows, software-pipelined: while the
// Gram reduction of row k runs, row k+1's 12 float4 loads are already in
// flight (double register set, ~24 x 16B outstanding per wave in steady
// state). This attacks the measured latency-boundness (cold dispatch: 834
// GB/s @ VALUBusy 2%) — wave lifetime amortizes 4 miss latencies instead of
// exposing one per wave. Single-pass Gram math (exact eps expansion):
//   sum_p = si^2*ni + sp^2*np - 2*si*sp*dot_ip + 2*eps*(si*Sa - sp*Sb) + D*eps^2
__global__ __launch_bounds__(256, 4) void row_loss_kernel(
    const float* __restrict__ emb,
    const int*   __restrict__ pos_idx,
    const int*   __restrict__ neg_idx,
    float*       __restrict__ block_part)
{
    const int tid  = threadIdx.x;
    const int lane = tid & 63;
    const int wid  = tid >> 6;
    const int wave = blockIdx.x * WAVES_PER_BLOCK + wid;
    const int base = wave * ROWS_PER_WAVE;

    // wave-uniform index loads (scalarized by the compiler)
    int pidx[ROWS_PER_WAVE], nidx[ROWS_PER_WAVE];
    #pragma unroll
    for (int k = 0; k < ROWS_PER_WAVE; ++k) {
        pidx[k] = pos_idx[base + k];
        nidx[k] = neg_idx[base + k];
    }

    const float4* e4 = (const float4*)emb;
    #define ROWPTR(r) (e4 + (size_t)(r) * F4_PER_ROW + lane)

    float4 ca[4], cb[4], cc[4];     // current row's 12 float4
    float4 na[4], nb[4], nc[4];     // prefetched next row
    #pragma unroll
    for (int j = 0; j < 4; ++j) {
        ca[j] = ROWPTR(base)[64 * j];
        cb[j] = ROWPTR(pidx[0])[64 * j];
        cc[j] = ROWPTR(nidx[0])[64 * j];
    }

    const float de2 = (float)DIM * EPS_F * EPS_F;
    float wave_acc = 0.f;

    #pragma unroll
    for (int k = 0; k < ROWS_PER_WAVE; ++k) {
        // issue next row's loads FIRST — they fly while we reduce this row
        if (k + 1 < ROWS_PER_WAVE) {
            #pragma unroll
            for (int j = 0; j < 4; ++j) {
                na[j] = ROWPTR(base + k + 1)[64 * j];
                nb[j] = ROWPTR(pidx[k + 1])[64 * j];
                nc[j] = ROWPTR(nidx[k + 1])[64 * j];
            }
        }

        float ni = 0.f, np_ = 0.f, nn = 0.f;   // squared norms
        float dip = 0.f, din = 0.f;            // dot(a,b), dot(a,c)
        float sa = 0.f, sb = 0.f, sc = 0.f;    // element sums (eps terms)
        #pragma unroll
        for (int j = 0; j < 4; ++j) {
            const float4 A = ca[j], B = cb[j], C = cc[j];
            ni  = fmaf(A.x,A.x,ni);  ni  = fmaf(A.y,A.y,ni);  ni  = fmaf(A.z,A.z,ni);  ni  = fmaf(A.w,A.w,ni);
            np_ = fmaf(B.x,B.x,np_); np_ = fmaf(B.y,B.y,np_); np_ = fmaf(B.z,B.z,np_); np_ = fmaf(B.w,B.w,np_);
            nn  = fmaf(C.x,C.x,nn);  nn  = fmaf(C.y,C.y,nn);  nn  = fmaf(C.z,C.z,nn);  nn  = fmaf(C.w,C.w,nn);
            dip = fmaf(A.x,B.x,dip); dip = fmaf(A.y,B.y,dip); dip = fmaf(A.z,B.z,dip); dip = fmaf(A.w,B.w,dip);
            din = fmaf(A.x,C.x,din); din = fmaf(A.y,C.y,din); din = fmaf(A.z,C.z,din); din = fmaf(A.w,C.w,din);
            sa += (A.x + A.y) + (A.z + A.w);
            sb += (B.x + B.y) + (B.z + B.w);
            sc += (C.x + C.y) + (C.z + C.w);
        }

        #pragma unroll
        for (int m = 1; m < 64; m <<= 1) {
            ni  += __shfl_xor(ni,  m, 64);
            np_ += __shfl_xor(np_, m, 64);
            nn  += __shfl_xor(nn,  m, 64);
            dip += __shfl_xor(dip, m, 64);
            din += __shfl_xor(din, m, 64);
            sa  += __shfl_xor(sa,  m, 64);
            sb  += __shfl_xor(sb,  m, 64);
            sc  += __shfl_xor(sc,  m, 64);
        }

        // uniform across lanes after butterfly — compute in all lanes
        const float si = 1.0f / fmaxf(sqrtf(ni),  EPS_F);
        const float sp = 1.0f / fmaxf(sqrtf(np_), EPS_F);
        const float sn = 1.0f / fmaxf(sqrtf(nn),  EPS_F);

        float sum_p = fmaf(si * si, ni, fmaf(sp * sp, np_, -2.f * si * sp * dip))
                    + 2.f * EPS_F * (si * sa - sp * sb) + de2;
        float sum_n = fmaf(si * si, ni, fmaf(sn * sn, nn, -2.f * si * sn * din))
                    + 2.f * EPS_F * (si * sa - sn * sc) + de2;

        float d_pos = sqrtf(fmaxf(sum_p, 0.f)) + EPS_F;
        float d_neg = sqrtf(fmaxf(sum_n, 0.f)) + EPS_F;
        float mq    = fmaxf(MARGIN_F - d_neg, EPS_F);
        wave_acc += fmaf(d_pos, d_pos, mq * mq);

        if (k + 1 < ROWS_PER_WAVE) {
            #pragma unroll
            for (int j = 0; j < 4; ++j) { ca[j] = na[j]; cb[j] = nb[j]; cc[j] = nc[j]; }
        }
    }
    #undef ROWPTR

    __shared__ float sm[WAVES_PER_BLOCK];
    if (lane == 0) sm[wid] = wave_acc;
    __syncthreads();
    if (tid == 0)
        block_part[blockIdx.x] = (sm[0] + sm[1]) + (sm[2] + sm[3]);
}

// 1024 block partials -> scalar. One block, 256 threads, 4 KiB read.
__global__ __launch_bounds__(256) void final_reduce_kernel(
    const float* __restrict__ part,
    float*       __restrict__ out)
{
    const int tid = threadIdx.x;
    const float4* p4 = (const float4*)part;   // 256 float4
    float4 v = p4[tid];
    float s = (v.x + v.y) + (v.z + v.w);
    #pragma unroll
    for (int m = 1; m < 64; m <<= 1) s += __shfl_xor(s, m, 64);

    __shared__ float sm[4];
    if ((tid & 63) == 0) sm[tid >> 6] = s;
    __syncthreads();
    if (tid == 0)
        out[0] = ((sm[0] + sm[1]) + (sm[2] + sm[3])) * (1.0f / (2.0f * (float)NROWS));
}

extern "C" void kernel_launch(void* const* d_in, const int* in_sizes, int n_in,
                              void* d_out, int out_size, void* d_ws, size_t ws_size,
                              hipStream_t stream) {
    const float* emb = (const float*)d_in[0];
    // d_in[1] = labels (unused by the loss itself)
    const int* pos = (const int*)d_in[2];
    const int* neg = (const int*)d_in[3];

    float* parts = (float*)d_ws;           // NBLOCKS floats of scratch
    float* out   = (float*)d_out;

    row_loss_kernel<<<NBLOCKS, 256, 0, stream>>>(emb, pos, neg, parts);
    final_reduce_kernel<<<1, 256, 0, stream>>>(parts, out);
}